// Round 19
// baseline (1238.492 us; speedup 1.0000x reference)
//
#include <hip/hip_runtime.h>
#include <stdint.h>

typedef _Float16 f16;
typedef __attribute__((ext_vector_type(4))) _Float16 f16x4;
typedef __attribute__((ext_vector_type(8))) _Float16 f16x8;
typedef __attribute__((ext_vector_type(4))) float f32x4;

#define BD 64      // state dim D
#define HW 512     // hidden width W
#define TT 16      // time points T
#define BR 16      // batch rows per group
#define NTHREADS 512
#define NGRP 32    // batch groups (512/16)
#define NCU 4      // CUs per group (W1 slice register-resident, 64 VGPR/lane)

// lgkm-only barrier: LDS producer->consumer, no vmcnt drain
#define LBAR() asm volatile("s_waitcnt lgkmcnt(0)\n\ts_barrier" ::: "memory")
#define VM_DRAIN() asm volatile("s_waitcnt vmcnt(0)" ::: "memory")

// Tsit5 coefficients
constexpr float cA21 = 0.161f;
constexpr float cA31 = -0.008480655492356989f, cA32 = 0.335480655492357f;
constexpr float cA41 = 2.8971530571054935f, cA42 = -6.359448489975075f, cA43 = 4.3622954328695815f;
constexpr float cA51 = 5.325864828439257f, cA52 = -11.748883564062828f, cA53 = 7.4955393428898365f, cA54 = -0.09249506636175525f;
constexpr float cA61 = 5.86145544294642f, cA62 = -12.92096931784711f, cA63 = 8.159367898576159f, cA64 = -0.071584973281401f, cA65 = -0.028269050394068383f;
constexpr float cB1 = 0.09646076681806523f, cB2 = 0.01f, cB3 = 0.4798896504144996f;
constexpr float cB4 = 1.379008574103742f, cB5 = -3.290069515436081f, cB6 = 2.324710524099774f;

__device__ __forceinline__ float softplus_f(float x) {
  return fmaxf(x, 0.0f) + __logf(1.0f + __expf(-fabsf(x)));
}

// convert W0 [512,64], W1 [512,512], W2 [64,512] (row-major f32) to fp16 in ws
__global__ void cvt_kernel(const float* __restrict__ w0,
                           const float* __restrict__ w1,
                           const float* __restrict__ w2,
                           f16* __restrict__ wsh) {
  int i = blockIdx.x * 512 + threadIdx.x;
  if (i < 32768) wsh[i] = (f16)w0[i];
  else if (i < 294912) wsh[i] = (f16)w1[i - 32768];
  else if (i < 327680) wsh[i] = (f16)w2[i - 294912];
}

__global__ __launch_bounds__(NTHREADS)
void ode_kernel(const float* __restrict__ ts,
                const float* __restrict__ y0,
                const float* __restrict__ b0,
                const float* __restrict__ b1,
                const float* __restrict__ b2,
                const f16* __restrict__ W0h,
                const f16* __restrict__ W1h,
                const f16* __restrict__ W2h,
                float* __restrict__ out,
                float* partials,
                unsigned int* flags,
                unsigned int* xcdbuf) {
  // W0 resident in LDS (64 KB), XOR-swizzled rows of 128 B
  __shared__ __align__(16) f16 w0s[512 * 64];
  __shared__ __align__(16) f16 h0buf[BR][HW + 8];
  __shared__ __align__(16) f16 h1buf[BR][128 + 8];
  __shared__ __align__(16) f16 atile[BR][BD + 8];
  __shared__ float b0s[512];     // layer-1 bias (f32)
  __shared__ float b1s[128];     // layer-2 bias slice (f32)
  __shared__ float hsteps[TT - 1];
  __shared__ int fastsh;

  const int tid  = threadIdx.x;
  const int wave = tid >> 6;
  const int lane = tid & 63;
  const int m = lane & 15;   // MFMA row/col index
  const int g = lane >> 4;   // lane group 0..3
  const int b = blockIdx.x;
  const int grp = b & 31;    // batch group; teammates {grp, grp+32, +64, +96}
  const int cuj = b >> 5;    // which quarter of W1/h1/K this CU owns
  const int row0 = grp * BR;
  const int cbase = wave * 64;  // layer-1 output-col base
  const int ntile = wave & 3;   // layer-3 output col tile (waves 0-3 compute+store)
  const int r0 = tid >> 6, d = tid & 63;   // per-thread output elems (r0,d),(r0+8,d)

  // publish this block's XCD id (read during stage-1 fallback exchange)
  if (tid == 0) {
    unsigned int myxcd = 0;
    asm volatile("s_getreg_b32 %0, hwreg(HW_REG_XCC_ID)" : "=s"(myxcd));
    __hip_atomic_store(&xcdbuf[b], myxcd, __ATOMIC_RELAXED, __HIP_MEMORY_SCOPE_AGENT);
  }

  // ---- register-resident weights: W1 slice only (highest read count) ----
  f16x8 w1r[16];
#pragma unroll
  for (int kt = 0; kt < 16; ++kt)
    w1r[kt] = *(const f16x8*)&W1h[(size_t)(cuj * 128 + wave * 16 + m) * HW + kt * 32 + g * 8];
  f16x8 w2r[4];  // 16 VGPR: W2 K-slice [cuj*128, +128) for out tile ntile
#pragma unroll
  for (int kt = 0; kt < 4; ++kt)
    w2r[kt] = *(const f16x8*)&W2h[(ntile * 16 + m) * HW + cuj * 128 + kt * 32 + g * 8];
  const float b2d = b2[d];

  // ---- stage W0 into LDS, XOR-swizzled (row = output col n, 128 B rows) ----
  for (int idx = tid; idx < 512 * 8; idx += NTHREADS) {
    const int row = idx >> 3, ch = idx & 7;            // ch = 16B chunk (8 f16)
    const f16x8 v = *(const f16x8*)&W0h[row * BD + ch * 8];
    *(f16x8*)((char*)w0s + row * 128 + ((ch * 16) ^ ((row & 7) << 4))) = v;
  }
  // bias tables
  b0s[tid] = b0[tid];
  if (tid < 128) b1s[tid] = b1[cuj * 128 + tid];

  // ---- y state in registers ----
  float yreg0 = y0[(row0 + r0) * BD + d];
  float yreg1 = y0[(row0 + r0 + 8) * BD + d];
  atile[r0][d] = (f16)yreg0;
  atile[r0 + 8][d] = (f16)yreg1;
  if (cuj == 0) {
    out[(row0 + r0) * (TT * BD) + d] = yreg0;
    out[(row0 + r0 + 8) * (TT * BD) + d] = yreg1;
  }
  if (tid < TT - 1) hsteps[tid] = (ts[tid + 1] - ts[tid]) * 0.25f;
  LBAR();

  int fstep = 0;              // total stages done
  unsigned int fseq = 0;      // fast-protocol sequence
  unsigned int fcnt = 0;      // fallback-protocol count
  bool fast = false;          // decided after stage 1
  unsigned int* const flagline = &flags[grp * 32];  // 128B line per group
  // words 0..15: per-(CU,wave) seq flags (fast); word 24: fetch_add counter (fallback)

  const int msw = (m & 7) << 4;   // W0 read-side swizzle ((cbase+nt*16+m)&7 == m&7)

  // one MLP eval of f(atile); k distributed into (KA,KB) on every CU
  auto feval = [&](int st, float& KA, float& KB) {
    // ---- layer 1 (operand-swapped): W0 from swizzled LDS as A; atile as B
    {
      f32x4 acc[4] = {{0,0,0,0},{0,0,0,0},{0,0,0,0},{0,0,0,0}};
#pragma unroll
      for (int kt = 0; kt < 2; ++kt) {
        const f16x8 a = *(const f16x8*)&atile[m][kt * 32 + g * 8];  // B-operand (atile^T)
#pragma unroll
        for (int nt = 0; nt < 4; ++nt) {
          const f16x8 bb = *(const f16x8*)((char*)w0s + (cbase + nt * 16 + m) * 128 +
                                           ((kt * 64 + g * 16) ^ msw));
          acc[nt] = __builtin_amdgcn_mfma_f32_16x16x32_f16(bb, a, acc[nt], 0, 0, 0);
        }
      }
#pragma unroll
      for (int nt = 0; nt < 4; ++nt) {
        const f32x4 bv = *(const f32x4*)&b0s[cbase + nt * 16 + g * 4];  // broadcast read
        f16x4 q;
#pragma unroll
        for (int j = 0; j < 4; ++j)
          q[j] = (f16)softplus_f(acc[nt][j] + bv[j]);
        *(f16x4*)&h0buf[m][cbase + nt * 16 + g * 4] = q;   // row r=m, 4 consecutive n
      }
    }
    LBAR();
    // ---- layer 2 (operand-swapped): W1 from REGISTERS as A; h0 from LDS as B
    {
      f32x4 acc1 = {0, 0, 0, 0};
#pragma unroll
      for (int kt = 0; kt < 16; ++kt) {
        const f16x8 a = *(const f16x8*)&h0buf[m][kt * 32 + g * 8];   // B-operand (h0^T)
        acc1 = __builtin_amdgcn_mfma_f32_16x16x32_f16(w1r[kt], a, acc1, 0, 0, 0);
      }
      const f32x4 bv = *(const f32x4*)&b1s[wave * 16 + g * 4];        // broadcast read
      f16x4 q;
#pragma unroll
      for (int j = 0; j < 4; ++j)
        q[j] = (f16)softplus_f(acc1[j] + bv[j]);
      *(f16x4*)&h1buf[m][wave * 16 + g * 4] = q;           // row r=m, 4 consecutive n
    }
    LBAR();
    // ---- layer 3: split-K partial (local K=128); waves 0-3 only
    if (wave < 4) {
      f32x4 acc3 = {0, 0, 0, 0};
#pragma unroll
      for (int kt = 0; kt < 4; ++kt) {
        const f16x8 a = *(const f16x8*)&h1buf[m][kt * 32 + g * 8];
        acc3 = __builtin_amdgcn_mfma_f32_16x16x32_f16(a, w2r[kt], acc3, 0, 0, 0);
      }
      float* const pb = partials + ((size_t)(grp * 6 + st) * 4 + cuj) * 1024;
      if (fast) {   // same-XCD: plain stores stay dirty in local L2
#pragma unroll
        for (int j = 0; j < 4; ++j)
          __hip_atomic_store(&pb[(g * 4 + j) * 64 + ntile * 16 + m], acc3[j],
                             __ATOMIC_RELAXED, __HIP_MEMORY_SCOPE_WORKGROUP);
      } else {      // fallback: write-through to LLC
#pragma unroll
        for (int j = 0; j < 4; ++j)
          __hip_atomic_store(&pb[(g * 4 + j) * 64 + ntile * 16 + m], acc3[j],
                             __ATOMIC_RELAXED, __HIP_MEMORY_SCOPE_AGENT);
      }
    }
    ++fstep;
    if (fast) {
      // ---- per-wave flag protocol: no block barrier.
      // Each producing wave publishes its own seq after ITS stores drain.
      ++fseq;
      if (wave < 4) {
        VM_DRAIN();
        if (lane == 0)
          __hip_atomic_store(&flagline[cuj * 4 + wave], fseq,
                             __ATOMIC_RELAXED, __HIP_MEMORY_SCOPE_WORKGROUP);
      }
      // all threads poll all 16 (CU,wave) flags: 16 uniform loads = 1 L2 RT/iter
      for (;;) {
        unsigned int mn = 0xFFFFFFFFu;
#pragma unroll
        for (int w = 0; w < 16; ++w) {
          const unsigned int f =
              __hip_atomic_load(&flagline[w], __ATOMIC_RELAXED, __HIP_MEMORY_SCOPE_AGENT);
          mn = f < mn ? f : mn;
        }
        if (mn >= fseq) break;
        __builtin_amdgcn_s_sleep(1);
      }
      asm volatile("" ::: "memory");   // keep gather loads after the poll exit
    } else {
      VM_DRAIN();
      LBAR();
      ++fcnt;
      if (tid == 0) {
        __hip_atomic_fetch_add(&flagline[24], 1u, __ATOMIC_RELEASE, __HIP_MEMORY_SCOPE_AGENT);
        const unsigned int tgt = 4u * fcnt;
        while (__hip_atomic_load(&flagline[24], __ATOMIC_ACQUIRE, __HIP_MEMORY_SCOPE_AGENT) < tgt)
          __builtin_amdgcn_s_sleep(1);
        if (fstep == 1) {   // teammates' xcdbuf now visible (release->acquire chain)
          const unsigned int x0 = __hip_atomic_load(&xcdbuf[grp],      __ATOMIC_RELAXED, __HIP_MEMORY_SCOPE_AGENT);
          const unsigned int x1 = __hip_atomic_load(&xcdbuf[grp + 32], __ATOMIC_RELAXED, __HIP_MEMORY_SCOPE_AGENT);
          const unsigned int x2 = __hip_atomic_load(&xcdbuf[grp + 64], __ATOMIC_RELAXED, __HIP_MEMORY_SCOPE_AGENT);
          const unsigned int x3 = __hip_atomic_load(&xcdbuf[grp + 96], __ATOMIC_RELAXED, __HIP_MEMORY_SCOPE_AGENT);
          fastsh = (x0 == x1 && x1 == x2 && x2 == x3) ? 1 : 0;
        }
      }
      __syncthreads();
      // keep fast-path flags in sync so the switch is seamless
      fseq = fcnt;
      if (wave < 4 && lane == 0)
        __hip_atomic_store(&flagline[cuj * 4 + wave], fseq,
                           __ATOMIC_RELAXED, __HIP_MEMORY_SCOPE_AGENT);
    }
    // gather: k[tid], k[tid+512] = sum of 4 CU partials (+ bias); idx=tid (coalesced)
    // agent loads bypass L1 and traverse the local L2 (hit dirty lines in fast path)
    const float* const q = partials + (size_t)(grp * 6 + st) * 4096;
    float s0 = 0.f, s1 = 0.f;
#pragma unroll
    for (int c = 0; c < 4; ++c) {
      s0 += __hip_atomic_load(q + c * 1024 + tid,       __ATOMIC_RELAXED, __HIP_MEMORY_SCOPE_AGENT);
      s1 += __hip_atomic_load(q + c * 1024 + tid + 512, __ATOMIC_RELAXED, __HIP_MEMORY_SCOPE_AGENT);
    }
    KA = s0 + b2d;
    KB = s1 + b2d;
    if (fstep == 1) fast = (fastsh != 0);   // decide protocol once, after stage 1
  };

  float k1a, k1b, k2a, k2b, k3a, k3b, k4a, k4b, k5a, k5b, k6a, k6b;

#define PUT_ATILE(E0, E1) \
  atile[r0][d] = (f16)(E0); atile[r0 + 8][d] = (f16)(E1); LBAR();

  for (int t = 0; t < TT - 1; ++t) {
    const float h = hsteps[t];
    for (int s = 0; s < 4; ++s) {
      feval(0, k1a, k1b);
      PUT_ATILE(yreg0 + h * (cA21 * k1a), yreg1 + h * (cA21 * k1b))
      feval(1, k2a, k2b);
      PUT_ATILE(yreg0 + h * (cA31 * k1a + cA32 * k2a),
                yreg1 + h * (cA31 * k1b + cA32 * k2b))
      feval(2, k3a, k3b);
      PUT_ATILE(yreg0 + h * (cA41 * k1a + cA42 * k2a + cA43 * k3a),
                yreg1 + h * (cA41 * k1b + cA42 * k2b + cA43 * k3b))
      feval(3, k4a, k4b);
      PUT_ATILE(yreg0 + h * (cA51 * k1a + cA52 * k2a + cA53 * k3a + cA54 * k4a),
                yreg1 + h * (cA51 * k1b + cA52 * k2b + cA53 * k3b + cA54 * k4b))
      feval(4, k5a, k5b);
      PUT_ATILE(yreg0 + h * (cA61 * k1a + cA62 * k2a + cA63 * k3a + cA64 * k4a + cA65 * k5a),
                yreg1 + h * (cA61 * k1b + cA62 * k2b + cA63 * k3b + cA64 * k4b + cA65 * k5b))
      feval(5, k6a, k6b);
      yreg0 += h * (cB1 * k1a + cB2 * k2a + cB3 * k3a + cB4 * k4a + cB5 * k5a + cB6 * k6a);
      yreg1 += h * (cB1 * k1b + cB2 * k2b + cB3 * k3b + cB4 * k4b + cB5 * k5b + cB6 * k6b);
      PUT_ATILE(yreg0, yreg1)
    }
    if (cuj == 0) {
      out[(row0 + r0) * (TT * BD) + (t + 1) * BD + d] = yreg0;
      out[(row0 + r0 + 8) * (TT * BD) + (t + 1) * BD + d] = yreg1;
    }
  }
#undef PUT_ATILE
}

extern "C" void kernel_launch(void* const* d_in, const int* in_sizes, int n_in,
                              void* d_out, int out_size, void* d_ws, size_t ws_size,
                              hipStream_t stream) {
  const float* ts = (const float*)d_in[0];
  const float* y0 = (const float*)d_in[1];
  const float* W0 = (const float*)d_in[2];
  const float* b0 = (const float*)d_in[3];
  const float* W1 = (const float*)d_in[4];
  const float* b1 = (const float*)d_in[5];
  const float* W2 = (const float*)d_in[6];
  const float* b2 = (const float*)d_in[7];
  // ws: [0,640K) fp16 weights | 655360: flags (4KB) | 659456: xcdbuf (512B)
  //     | 663552: k-partials (3MB)
  f16* wsh = (f16*)d_ws;
  unsigned int* flags  = (unsigned int*)((char*)d_ws + 655360);
  unsigned int* xcdbuf = (unsigned int*)((char*)d_ws + 659456);
  float* partials = (float*)((char*)d_ws + 663552);

  cvt_kernel<<<640, 512, 0, stream>>>(W0, W1, W2, wsh);
  hipMemsetAsync((char*)d_ws + 655360, 0, 8192, stream);
  ode_kernel<<<NGRP * NCU, NTHREADS, 0, stream>>>(ts, y0, b0, b1, b2,
                                                  wsh, wsh + 32768, wsh + 294912,
                                                  (float*)d_out, partials, flags, xcdbuf);
}

// Round 20
// 1076.516 us; speedup vs baseline: 1.1505x; 1.1505x over previous
//
#include <hip/hip_runtime.h>
#include <stdint.h>

typedef _Float16 f16;
typedef __attribute__((ext_vector_type(4))) _Float16 f16x4;
typedef __attribute__((ext_vector_type(8))) _Float16 f16x8;
typedef __attribute__((ext_vector_type(4))) float f32x4;

#define BD 64      // state dim D
#define HW 512     // hidden width W
#define TT 16      // time points T
#define BR 16      // batch rows per group
#define NTHREADS 512
#define NGRP 32    // batch groups (512/16)
#define NCU 4      // CUs per group (W1 slice register-resident, 64 VGPR/lane)

// lgkm-only barrier: LDS producer->consumer, no vmcnt drain
#define LBAR() asm volatile("s_waitcnt lgkmcnt(0)\n\ts_barrier" ::: "memory")
#define VM_DRAIN() asm volatile("s_waitcnt vmcnt(0)" ::: "memory")

// Tsit5 coefficients
constexpr float cA21 = 0.161f;
constexpr float cA31 = -0.008480655492356989f, cA32 = 0.335480655492357f;
constexpr float cA41 = 2.8971530571054935f, cA42 = -6.359448489975075f, cA43 = 4.3622954328695815f;
constexpr float cA51 = 5.325864828439257f, cA52 = -11.748883564062828f, cA53 = 7.4955393428898365f, cA54 = -0.09249506636175525f;
constexpr float cA61 = 5.86145544294642f, cA62 = -12.92096931784711f, cA63 = 8.159367898576159f, cA64 = -0.071584973281401f, cA65 = -0.028269050394068383f;
constexpr float cB1 = 0.09646076681806523f, cB2 = 0.01f, cB3 = 0.4798896504144996f;
constexpr float cB4 = 1.379008574103742f, cB5 = -3.290069515436081f, cB6 = 2.324710524099774f;

__device__ __forceinline__ float softplus_f(float x) {
  return fmaxf(x, 0.0f) + __logf(1.0f + __expf(-fabsf(x)));
}

// convert W0 [512,64], W1 [512,512], W2 [64,512] (row-major f32) to fp16 in ws
__global__ void cvt_kernel(const float* __restrict__ w0,
                           const float* __restrict__ w1,
                           const float* __restrict__ w2,
                           f16* __restrict__ wsh) {
  int i = blockIdx.x * 512 + threadIdx.x;
  if (i < 32768) wsh[i] = (f16)w0[i];
  else if (i < 294912) wsh[i] = (f16)w1[i - 32768];
  else if (i < 327680) wsh[i] = (f16)w2[i - 294912];
}

__global__ __launch_bounds__(NTHREADS)
void ode_kernel(const float* __restrict__ ts,
                const float* __restrict__ y0,
                const float* __restrict__ b0,
                const float* __restrict__ b1,
                const float* __restrict__ b2,
                const f16* __restrict__ W0h,
                const f16* __restrict__ W1h,
                const f16* __restrict__ W2h,
                float* __restrict__ out,
                float* partials,
                unsigned int* flags,
                unsigned int* xcdbuf) {
  // W0 resident in LDS (64 KB), XOR-swizzled rows of 128 B
  __shared__ __align__(16) f16 w0s[512 * 64];
  __shared__ __align__(16) f16 h0buf[BR][HW + 8];
  __shared__ __align__(16) f16 h1buf[BR][128 + 8];
  __shared__ __align__(16) f16 atile[BR][BD + 8];
  __shared__ float b0s[512];     // layer-1 bias (f32)
  __shared__ float b1s[128];     // layer-2 bias slice (f32)
  __shared__ float hsteps[TT - 1];
  __shared__ int fastsh;

  const int tid  = threadIdx.x;
  const int wave = tid >> 6;
  const int lane = tid & 63;
  const int m = lane & 15;   // MFMA row/col index
  const int g = lane >> 4;   // lane group 0..3
  const int b = blockIdx.x;
  const int grp = b & 31;    // batch group; teammates {grp, grp+32, +64, +96}
  const int cuj = b >> 5;    // which quarter of W1/h1/K this CU owns
  const int row0 = grp * BR;
  const int cbase = wave * 64;  // layer-1 output-col base
  const int ntile = wave & 3;   // layer-3 output col tile (waves 0-3 compute+store)
  const int r0 = tid >> 6, d = tid & 63;   // per-thread output elems (r0,d),(r0+8,d)

  // publish this block's XCD id (read during stage-1 fallback exchange)
  if (tid == 0) {
    unsigned int myxcd = 0;
    asm volatile("s_getreg_b32 %0, hwreg(HW_REG_XCC_ID)" : "=s"(myxcd));
    __hip_atomic_store(&xcdbuf[b], myxcd, __ATOMIC_RELAXED, __HIP_MEMORY_SCOPE_AGENT);
  }

  // ---- register-resident weights: W1 slice only (highest read count) ----
  // lane (m,g) of wave w needs W1slice[w*16+m][kt*32+g*8 .. +8], kt=0..15 -> 64 VGPR
  f16x8 w1r[16];
#pragma unroll
  for (int kt = 0; kt < 16; ++kt)
    w1r[kt] = *(const f16x8*)&W1h[(size_t)(cuj * 128 + wave * 16 + m) * HW + kt * 32 + g * 8];
  f16x8 w2r[4];  // 16 VGPR: W2 K-slice [cuj*128, +128) for out tile ntile
#pragma unroll
  for (int kt = 0; kt < 4; ++kt)
    w2r[kt] = *(const f16x8*)&W2h[(ntile * 16 + m) * HW + cuj * 128 + kt * 32 + g * 8];
  const float b2d = b2[d];

  // ---- stage W0 into LDS, XOR-swizzled (row = output col n, 128 B rows) ----
  for (int idx = tid; idx < 512 * 8; idx += NTHREADS) {
    const int row = idx >> 3, ch = idx & 7;            // ch = 16B chunk (8 f16)
    const f16x8 v = *(const f16x8*)&W0h[row * BD + ch * 8];
    *(f16x8*)((char*)w0s + row * 128 + ((ch * 16) ^ ((row & 7) << 4))) = v;
  }
  // bias tables
  b0s[tid] = b0[tid];
  if (tid < 128) b1s[tid] = b1[cuj * 128 + tid];

  // ---- y state in registers ----
  float yreg0 = y0[(row0 + r0) * BD + d];
  float yreg1 = y0[(row0 + r0 + 8) * BD + d];
  atile[r0][d] = (f16)yreg0;
  atile[r0 + 8][d] = (f16)yreg1;
  if (cuj == 0) {
    out[(row0 + r0) * (TT * BD) + d] = yreg0;
    out[(row0 + r0 + 8) * (TT * BD) + d] = yreg1;
  }
  if (tid < TT - 1) hsteps[tid] = (ts[tid + 1] - ts[tid]) * 0.25f;
  LBAR();

  int fstep = 0;              // total stages done
  unsigned int fseq = 0;      // fast-protocol sequence
  unsigned int fcnt = 0;      // fallback-protocol count
  bool fast = false;          // decided after stage 1
  unsigned int* const flagline = &flags[grp * 32];  // 128B line per group
  // words 0..3: per-CU seq flags (fast); word 16: fetch_add counter (fallback)

  const int msw = (m & 7) << 4;   // W0 read-side swizzle ((cbase+nt*16+m)&7 == m&7)

  // one MLP eval of f(atile); k distributed into (KA,KB) on every CU
  auto feval = [&](int st, float& KA, float& KB) {
    // ---- layer 1 (operand-swapped): W0 from swizzled LDS as A; atile as B
    {
      f32x4 acc[4] = {{0,0,0,0},{0,0,0,0},{0,0,0,0},{0,0,0,0}};
#pragma unroll
      for (int kt = 0; kt < 2; ++kt) {
        const f16x8 a = *(const f16x8*)&atile[m][kt * 32 + g * 8];  // B-operand (atile^T)
#pragma unroll
        for (int nt = 0; nt < 4; ++nt) {
          const f16x8 bb = *(const f16x8*)((char*)w0s + (cbase + nt * 16 + m) * 128 +
                                           ((kt * 64 + g * 16) ^ msw));
          acc[nt] = __builtin_amdgcn_mfma_f32_16x16x32_f16(bb, a, acc[nt], 0, 0, 0);
        }
      }
#pragma unroll
      for (int nt = 0; nt < 4; ++nt) {
        const f32x4 bv = *(const f32x4*)&b0s[cbase + nt * 16 + g * 4];  // broadcast read
        f16x4 q;
#pragma unroll
        for (int j = 0; j < 4; ++j)
          q[j] = (f16)softplus_f(acc[nt][j] + bv[j]);
        *(f16x4*)&h0buf[m][cbase + nt * 16 + g * 4] = q;   // row r=m, 4 consecutive n
      }
    }
    LBAR();
    // ---- layer 2 (operand-swapped): W1 from REGISTERS as A; h0 from LDS as B
    {
      f32x4 acc1 = {0, 0, 0, 0};
#pragma unroll
      for (int kt = 0; kt < 16; ++kt) {
        const f16x8 a = *(const f16x8*)&h0buf[m][kt * 32 + g * 8];   // B-operand (h0^T)
        acc1 = __builtin_amdgcn_mfma_f32_16x16x32_f16(w1r[kt], a, acc1, 0, 0, 0);
      }
      const f32x4 bv = *(const f32x4*)&b1s[wave * 16 + g * 4];        // broadcast read
      f16x4 q;
#pragma unroll
      for (int j = 0; j < 4; ++j)
        q[j] = (f16)softplus_f(acc1[j] + bv[j]);
      *(f16x4*)&h1buf[m][wave * 16 + g * 4] = q;           // row r=m, 4 consecutive n
    }
    LBAR();
    // ---- layer 3: split-K partial (local K=128); waves 0-3 only
    if (wave < 4) {
      f32x4 acc3 = {0, 0, 0, 0};
#pragma unroll
      for (int kt = 0; kt < 4; ++kt) {
        const f16x8 a = *(const f16x8*)&h1buf[m][kt * 32 + g * 8];
        acc3 = __builtin_amdgcn_mfma_f32_16x16x32_f16(a, w2r[kt], acc3, 0, 0, 0);
      }
      float* const pb = partials + ((size_t)(grp * 6 + st) * 4 + cuj) * 1024;
      if (fast) {   // same-XCD: plain stores stay dirty in local L2
#pragma unroll
        for (int j = 0; j < 4; ++j)
          __hip_atomic_store(&pb[(g * 4 + j) * 64 + ntile * 16 + m], acc3[j],
                             __ATOMIC_RELAXED, __HIP_MEMORY_SCOPE_WORKGROUP);
      } else {      // fallback: write-through to LLC
#pragma unroll
        for (int j = 0; j < 4; ++j)
          __hip_atomic_store(&pb[(g * 4 + j) * 64 + ntile * 16 + m], acc3[j],
                             __ATOMIC_RELAXED, __HIP_MEMORY_SCOPE_AGENT);
      }
    }
    VM_DRAIN();          // own partial stores at their coherence point
    LBAR();              // all waves of this block drained
    ++fstep;
    if (fast) {
      ++fseq;
      if (tid == 0)
        __hip_atomic_store(&flagline[cuj], fseq, __ATOMIC_RELAXED, __HIP_MEMORY_SCOPE_WORKGROUP);
      // all-thread poll: flag addresses are lane-uniform -> 4 broadcast L2 loads
      // per wave per iteration; removes tid0-spin handoff + __syncthreads
      unsigned int f0, f1, f2, f3;
      for (;;) {
        f0 = __hip_atomic_load(&flagline[0], __ATOMIC_RELAXED, __HIP_MEMORY_SCOPE_AGENT);
        f1 = __hip_atomic_load(&flagline[1], __ATOMIC_RELAXED, __HIP_MEMORY_SCOPE_AGENT);
        f2 = __hip_atomic_load(&flagline[2], __ATOMIC_RELAXED, __HIP_MEMORY_SCOPE_AGENT);
        f3 = __hip_atomic_load(&flagline[3], __ATOMIC_RELAXED, __HIP_MEMORY_SCOPE_AGENT);
        if (f0 >= fseq && f1 >= fseq && f2 >= fseq && f3 >= fseq) break;
        __builtin_amdgcn_s_sleep(1);
      }
      asm volatile("" ::: "memory");   // keep gather loads after the poll exit
    } else {
      ++fcnt;
      if (tid == 0) {
        __hip_atomic_fetch_add(&flagline[16], 1u, __ATOMIC_RELEASE, __HIP_MEMORY_SCOPE_AGENT);
        const unsigned int tgt = 4u * fcnt;
        while (__hip_atomic_load(&flagline[16], __ATOMIC_ACQUIRE, __HIP_MEMORY_SCOPE_AGENT) < tgt)
          __builtin_amdgcn_s_sleep(1);
        if (fstep == 1) {   // teammates' xcdbuf now visible (release->acquire chain)
          const unsigned int x0 = __hip_atomic_load(&xcdbuf[grp],      __ATOMIC_RELAXED, __HIP_MEMORY_SCOPE_AGENT);
          const unsigned int x1 = __hip_atomic_load(&xcdbuf[grp + 32], __ATOMIC_RELAXED, __HIP_MEMORY_SCOPE_AGENT);
          const unsigned int x2 = __hip_atomic_load(&xcdbuf[grp + 64], __ATOMIC_RELAXED, __HIP_MEMORY_SCOPE_AGENT);
          const unsigned int x3 = __hip_atomic_load(&xcdbuf[grp + 96], __ATOMIC_RELAXED, __HIP_MEMORY_SCOPE_AGENT);
          fastsh = (x0 == x1 && x1 == x2 && x2 == x3) ? 1 : 0;
        }
      }
      __syncthreads();
    }
    // gather: k[tid], k[tid+512] = sum of 4 CU partials (+ bias); idx=tid (coalesced)
    // agent loads bypass L1 and traverse the local L2 (hit dirty lines in fast path)
    const float* const q = partials + (size_t)(grp * 6 + st) * 4096;
    float s0 = 0.f, s1 = 0.f;
#pragma unroll
    for (int c = 0; c < 4; ++c) {
      s0 += __hip_atomic_load(q + c * 1024 + tid,       __ATOMIC_RELAXED, __HIP_MEMORY_SCOPE_AGENT);
      s1 += __hip_atomic_load(q + c * 1024 + tid + 512, __ATOMIC_RELAXED, __HIP_MEMORY_SCOPE_AGENT);
    }
    KA = s0 + b2d;
    KB = s1 + b2d;
    if (fstep == 1) fast = (fastsh != 0);   // decide protocol once, after stage 1
  };

  float k1a, k1b, k2a, k2b, k3a, k3b, k4a, k4b, k5a, k5b, k6a, k6b;

#define PUT_ATILE(E0, E1) \
  atile[r0][d] = (f16)(E0); atile[r0 + 8][d] = (f16)(E1); LBAR();

  for (int t = 0; t < TT - 1; ++t) {
    const float h = hsteps[t];
    for (int s = 0; s < 4; ++s) {
      feval(0, k1a, k1b);
      PUT_ATILE(yreg0 + h * (cA21 * k1a), yreg1 + h * (cA21 * k1b))
      feval(1, k2a, k2b);
      PUT_ATILE(yreg0 + h * (cA31 * k1a + cA32 * k2a),
                yreg1 + h * (cA31 * k1b + cA32 * k2b))
      feval(2, k3a, k3b);
      PUT_ATILE(yreg0 + h * (cA41 * k1a + cA42 * k2a + cA43 * k3a),
                yreg1 + h * (cA41 * k1b + cA42 * k2b + cA43 * k3b))
      feval(3, k4a, k4b);
      PUT_ATILE(yreg0 + h * (cA51 * k1a + cA52 * k2a + cA53 * k3a + cA54 * k4a),
                yreg1 + h * (cA51 * k1b + cA52 * k2b + cA53 * k3b + cA54 * k4b))
      feval(4, k5a, k5b);
      PUT_ATILE(yreg0 + h * (cA61 * k1a + cA62 * k2a + cA63 * k3a + cA64 * k4a + cA65 * k5a),
                yreg1 + h * (cA61 * k1b + cA62 * k2b + cA63 * k3b + cA64 * k4b + cA65 * k5b))
      feval(5, k6a, k6b);
      yreg0 += h * (cB1 * k1a + cB2 * k2a + cB3 * k3a + cB4 * k4a + cB5 * k5a + cB6 * k6a);
      yreg1 += h * (cB1 * k1b + cB2 * k2b + cB3 * k3b + cB4 * k4b + cB5 * k5b + cB6 * k6b);
      PUT_ATILE(yreg0, yreg1)
    }
    if (cuj == 0) {
      out[(row0 + r0) * (TT * BD) + (t + 1) * BD + d] = yreg0;
      out[(row0 + r0 + 8) * (TT * BD) + (t + 1) * BD + d] = yreg1;
    }
  }
#undef PUT_ATILE
}

extern "C" void kernel_launch(void* const* d_in, const int* in_sizes, int n_in,
                              void* d_out, int out_size, void* d_ws, size_t ws_size,
                              hipStream_t stream) {
  const float* ts = (const float*)d_in[0];
  const float* y0 = (const float*)d_in[1];
  const float* W0 = (const float*)d_in[2];
  const float* b0 = (const float*)d_in[3];
  const float* W1 = (const float*)d_in[4];
  const float* b1 = (const float*)d_in[5];
  const float* W2 = (const float*)d_in[6];
  const float* b2 = (const float*)d_in[7];
  // ws: [0,640K) fp16 weights | 655360: flags (4KB) | 659456: xcdbuf (512B)
  //     | 663552: k-partials (3MB)
  f16* wsh = (f16*)d_ws;
  unsigned int* flags  = (unsigned int*)((char*)d_ws + 655360);
  unsigned int* xcdbuf = (unsigned int*)((char*)d_ws + 659456);
  float* partials = (float*)((char*)d_ws + 663552);

  cvt_kernel<<<640, 512, 0, stream>>>(W0, W1, W2, wsh);
  hipMemsetAsync((char*)d_ws + 655360, 0, 8192, stream);
  ode_kernel<<<NGRP * NCU, NTHREADS, 0, stream>>>(ts, y0, b0, b1, b2,
                                                  wsh, wsh + 32768, wsh + 294912,
                                                  (float*)d_out, partials, flags, xcdbuf);
}